// Round 1
// 2403.007 us; speedup vs baseline: 1.1482x; 1.1482x over previous
//
#include <hip/hip_runtime.h>

// Residual quantizer: N=65536 vectors (D=128), M=8 stages, K=256 codewords.
// Structurally 1 wave/SIMD (65536 threads); all hiding must come from ILP.
//
// R2->R3: R2 was LDS operand-delivery bound, not VALU bound. Every lane read
// the full 512 B codeword per k (32x ds_read_b128 broadcast): 4 waves/CU x
// 32 instr x 1024 B = 128 KB LDS return traffic per codeword (~1024 cyc)
// vs ~340 VALU cyc -> VALUBusy 29% ~= 340/1024. Fix: quad-split. Each quad
// of 4 lanes owns 4 vectors; lane q holds the D-interleaved quarter
// {8k+2q, 8k+2q+1} of each. Per codeword a lane does 16x ds_read_b64, each
// feeding 8 FMAs (4 vec x 2 chains): LDS/CU/codeword drops 4x to 32 KB
// (~256 cyc) while VALU is ~380 cyc -> VALU-bound.
//
// Numerics (absmax must stay 0.0): every pairwise-8 chain j (elements
// i == j mod 8, mul + 15 sequential fma) is kept WHOLE in one lane; lane q
// owns chains 2q and 2q+1. Combine: s_q = p_{2q}+p_{2q+1}, then DPP
// quad_perm butterfly u1 = s + xor1(s); u2 = u1 + xor2(u1) gives
// ((p0+p1)+(p2+p3)) + ((p4+p5)+(p6+p7)) bit-exactly in ALL 4 lanes (fp32
// add is commutative bitwise) -> argmin is quad-uniform, no divergence.
// dist = (rn - 2*dot) + cn, cn/rn chain code, strict <, and the
// rec += c; res = x - rec association are unchanged from R2.

constexpr int NV = 65536;
constexpr int DD = 128;
constexpr int MS = 8;
constexpr int KC = 256;
constexpr int CH = 112;   // codebook rows per LDS chunk: 112*128*4 = 57344 B

template<int CTRL>
__device__ __forceinline__ float quad_bfly_add(float v) {
    // v + quad_perm<CTRL>(v); 0xB1 = [1,0,3,2] (xor1), 0x4E = [2,3,0,1] (xor2)
    int p = __builtin_amdgcn_update_dpp(__float_as_int(v), __float_as_int(v),
                                        CTRL, 0xF, 0xF, true);
    return v + __int_as_float(p);
}

__global__ __launch_bounds__(256, 1)
void rq_kernel(const float* __restrict__ x,
               const float* __restrict__ cb,
               float* __restrict__ out)
{
    const int tid = threadIdx.x;
    const int q   = tid & 3;                 // D-quarter / chain pair {2q,2q+1}
    const int g   = tid >> 2;                // vector group within block
    const size_t vbase = (size_t)blockIdx.x * 256 + (size_t)g * 4;

    __shared__ float sC[CH * DD];   // 57344 B
    __shared__ float cn_s[CH];      // 448 B

    // Per-lane state: 4 vectors' D-quarters. rA/rB: res chains 2q / 2q+1,
    // cA/cB: rec. Element k maps to vector float index 8k+2q (+1 for B).
    float rA[4][16], rB[4][16], cA[4][16], cB[4][16];

    #pragma unroll
    for (int v = 0; v < 4; ++v) {
        const float* xr = x + (vbase + v) * DD + 2 * q;
        #pragma unroll
        for (int k = 0; k < 16; ++k) {
            float2 t = *(const float2*)(xr + 8 * k);
            rA[v][k] = t.x; rB[v][k] = t.y;
            cA[v][k] = 0.0f; cB[v][k] = 0.0f;
        }
    }

    float* out_recon = out;                                  // (N, D)
    float* out_codes = out + (size_t)NV * DD;                // (N, M, K)
    float* out_side  = out_codes + (size_t)NV * MS * KC;     // (M, N, D)

    for (int m = 0; m < MS; ++m) {
        const float* C = cb + (size_t)m * KC * DD;

        // ||res||^2 per vector: chains 2q,2q+1 + quad butterfly (bit-exact
        // replica of ((p0+p1)+(p2+p3))+((p4+p5)+(p6+p7)))
        float rn[4];
        #pragma unroll
        for (int v = 0; v < 4; ++v) {
            float pa = rA[v][0] * rA[v][0];
            float pb = rB[v][0] * rB[v][0];
            #pragma unroll
            for (int k = 1; k < 16; ++k) {
                pa += rA[v][k] * rA[v][k];
                pb += rB[v][k] * rB[v][k];
            }
            float s = pa + pb;
            s = quad_bfly_add<0xB1>(s);
            s = quad_bfly_add<0x4E>(s);
            rn[v] = s;
        }

        float best[4]; int bi[4];
        #pragma unroll
        for (int v = 0; v < 4; ++v) { best[v] = 3.402823466e38f; bi[v] = 0; }

        for (int base = 0; base < KC; base += CH) {
            const int rows = (KC - base) < CH ? (KC - base) : CH;

            __syncthreads();   // prior chunk's readers done before overwrite

            // stage chunk: coalesced float4 global->LDS
            {
                const float4* g4 = (const float4*)(C + (size_t)base * DD);
                float4* s4 = (float4*)sC;
                const int nf4 = rows * (DD / 4);
                for (int i = tid; i < nf4; i += 256) s4[i] = g4[i];
            }
            // cn for this chunk (from global; bitwise-same as R2/R1)
            if (tid < rows) {
                const float* cr = C + (size_t)(base + tid) * DD;
                float p[8];
                #pragma unroll
                for (int j = 0; j < 8; ++j) { float v = cr[j]; p[j] = v * v; }
                #pragma unroll
                for (int i = 8; i < DD; i += 8) {
                    #pragma unroll
                    for (int j = 0; j < 8; ++j) { float v = cr[i + j]; p[j] += v * v; }
                }
                cn_s[tid] = ((p[0]+p[1]) + (p[2]+p[3])) + ((p[4]+p[5]) + (p[6]+p[7]));
            }
            __syncthreads();

            #pragma unroll 2
            for (int kk = 0; kk < rows; ++kk) {
                const float* row = sC + kk * DD + 2 * q;   // this lane's quarter
                float pa[4], pb[4];
                {   // k = 0: chain init is a MUL (matches reference chain head)
                    float2 cv = *(const float2*)(row);
                    #pragma unroll
                    for (int v = 0; v < 4; ++v) {
                        pa[v] = rA[v][0] * cv.x;
                        pb[v] = rB[v][0] * cv.y;
                    }
                }
                #pragma unroll
                for (int k = 1; k < 16; ++k) {
                    float2 cv = *(const float2*)(row + 8 * k);  // ds_read_b64
                    #pragma unroll
                    for (int v = 0; v < 4; ++v) {
                        pa[v] += rA[v][k] * cv.x;
                        pb[v] += rB[v][k] * cv.y;
                    }
                }
                const float cn = cn_s[kk];
                #pragma unroll
                for (int v = 0; v < 4; ++v) {
                    float s = pa[v] + pb[v];            // p_{2q} + p_{2q+1}
                    s = quad_bfly_add<0xB1>(s);         // + xor1 neighbor
                    s = quad_bfly_add<0x4E>(s);         // + xor2 neighbor
                    float dist = (rn[v] - 2.0f * s) + cn;   // reference association
                    if (dist < best[v]) { best[v] = dist; bi[v] = base + kk; }  // strict <
                }
            }
        }

        // rec += c ; res = x - rec (element-wise, this lane's quarter only)
        #pragma unroll
        for (int v = 0; v < 4; ++v) {
            const size_t n = vbase + v;
            const float* cw = C + (size_t)bi[v] * DD + 2 * q;
            const float* xr = x + n * DD + 2 * q;
            float* so = out_side + ((size_t)m * NV + n) * DD + 2 * q;
            #pragma unroll
            for (int k = 0; k < 16; ++k) {
                float2 cv = *(const float2*)(cw + 8 * k);
                float2 xv = *(const float2*)(xr + 8 * k);
                cA[v][k] += cv.x; cB[v][k] += cv.y;
                rA[v][k] = xv.x - cA[v][k];
                rB[v][k] = xv.y - cB[v][k];
                float2 ov; ov.x = cA[v][k]; ov.y = cB[v][k];
                *(float2*)(so + 8 * k) = ov;
            }
        }

        // one-hot codes: lane q writes the FULL row of vector vbase+q
        // (all quad lanes hold identical bi[0..3], so bi[q] is that
        // vector's index) -- same store pattern as R2.
        {
            const size_t n = vbase + q;
            float* crow = out_codes + n * (size_t)(MS * KC) + (size_t)m * KC;
            const int b = bi[q];
            #pragma unroll
            for (int j = 0; j < KC; j += 4) {
                float4 w;
                w.x = (b == j    ) ? 1.0f : 0.0f;
                w.y = (b == j + 1) ? 1.0f : 0.0f;
                w.z = (b == j + 2) ? 1.0f : 0.0f;
                w.w = (b == j + 3) ? 1.0f : 0.0f;
                *(float4*)(crow + j) = w;
            }
        }
    }

    // final recon (this lane's quarters)
    #pragma unroll
    for (int v = 0; v < 4; ++v) {
        float* ro = out_recon + (vbase + v) * DD + 2 * q;
        #pragma unroll
        for (int k = 0; k < 16; ++k) {
            float2 ov; ov.x = cA[v][k]; ov.y = cB[v][k];
            *(float2*)(ro + 8 * k) = ov;
        }
    }
}

extern "C" void kernel_launch(void* const* d_in, const int* in_sizes, int n_in,
                              void* d_out, int out_size, void* d_ws, size_t ws_size,
                              hipStream_t stream)
{
    const float* x  = (const float*)d_in[0];
    const float* cb = (const float*)d_in[1];
    float* out = (float*)d_out;
    rq_kernel<<<dim3(NV / 256), dim3(256), 0, stream>>>(x, cb, out);
}

// Round 2
// 1617.079 us; speedup vs baseline: 1.7063x; 1.4860x over previous
//
#include <hip/hip_runtime.h>

// Residual quantizer: N=65536 vectors (D=128), M=8 stages, K=256 codewords.
//
// R3->R4: R3 was latency-bound at the structural occupancy floor (1 wave/SIMD,
// VALUBusy 20%, all throughput floors ~250-450us vs 1771us measured) and was
// spilling (256 live floats/lane > 256 VGPRs). Fix: 8 lanes per vector
// (one pairwise-8 chain per lane), 4 vectors per 8-lane group -> 131072
// threads, 512 blocks, 2 blocks/CU, 2 waves/SIMD; per-lane state halves to
// 128 floats (no spills, launch_bounds(256,2)). Codebook staged TRANSPOSED
// into chain-major LDS (chain stride 20 dwords: 16B-aligned b128 reads, banks
// c*20+4t mod 32 = {0,20,8,28,16,4,24,12}+{0..3} disjoint -> 0 conflicts).
//
// Numerics (absmax must stay 0.0): each pairwise-8 chain j (mul + 15
// sequential fma over elements 8k+j) lives WHOLE in lane j of the group.
// Combine replicates ((p0+p1)+(p2+p3))+((p4+p5)+(p6+p7)) bitwise:
//   s1 = p + dpp_xor1(p)          (quad_perm 0xB1)
//   s2 = s1 + dpp_xor2(s1)        (quad_perm 0x4E)  -> lanes 0-3: T0, 4-7: T1
//   dot = s2 + dpp_half_mirror(s2)(0x141, lane i<->7-i within 8)  -> T0+T1
// fp32 add is bitwise-commutative, so all 8 lanes hold identical bits ->
// argmin (strict <, dist = (rn - 2*dot) + cn) is group-uniform, no divergence.
// rec += c; res = x - rec elementwise order unchanged.

constexpr int NV = 65536;
constexpr int DD = 128;
constexpr int MS = 8;
constexpr int KC = 256;
constexpr int CH = 112;    // codebook rows per LDS chunk
constexpr int CST = 20;    // chain stride in dwords (16B-aligned, conflict-free)
constexpr int RST = 8 * CST;  // row stride in dwords = 160 (640 B)

template<int CTRL>
__device__ __forceinline__ float bfly_add(float v) {
    // v + dpp<CTRL>(v); 0xB1 = quad xor1, 0x4E = quad xor2, 0x141 = row_half_mirror
    int p = __builtin_amdgcn_update_dpp(__float_as_int(v), __float_as_int(v),
                                        CTRL, 0xF, 0xF, true);
    return v + __int_as_float(p);
}

__global__ __launch_bounds__(256, 2)
void rq_kernel(const float* __restrict__ x,
               const float* __restrict__ cb,
               float* __restrict__ out)
{
    const int tid = threadIdx.x;
    const int c   = tid & 7;                  // chain owned (elements 8k+c)
    const int grp = tid >> 3;                 // 8-lane group in block (0..31)
    const size_t vbase = (size_t)blockIdx.x * 128 + (size_t)grp * 4;

    __shared__ __align__(16) float sC[CH * RST];   // 71680 B, chain-major+pad
    __shared__ float cn_s[CH];                     // 448 B

    // Per-lane state: chain c of 4 vectors. rA = res, cA = rec.
    // Element k of chain = vector float index 8k+c.
    float rA[4][16], cA[4][16];

    #pragma unroll
    for (int v = 0; v < 4; ++v) {
        const float* xr = x + (vbase + v) * DD + c;
        #pragma unroll
        for (int k = 0; k < 16; ++k) {
            rA[v][k] = xr[8 * k];
            cA[v][k] = 0.0f;
        }
    }

    float* out_recon = out;                                  // (N, D)
    float* out_codes = out + (size_t)NV * DD;                // (N, M, K)
    float* out_side  = out_codes + (size_t)NV * MS * KC;     // (M, N, D)

    for (int m = 0; m < MS; ++m) {
        const float* C = cb + (size_t)m * KC * DD;

        // ||res||^2 per vector: own chain sequential, then exact combine tree
        float rn[4];
        #pragma unroll
        for (int v = 0; v < 4; ++v) {
            float p = rA[v][0] * rA[v][0];
            #pragma unroll
            for (int k = 1; k < 16; ++k) p += rA[v][k] * rA[v][k];
            p = bfly_add<0xB1>(p);     // p_c + p_{c^1}
            p = bfly_add<0x4E>(p);     // + (p_{c^2}+p_{c^3}) -> T_h
            p = bfly_add<0x141>(p);    // T0 + T1 (half mirror)
            rn[v] = p;
        }

        float best[4]; int bi[4];
        #pragma unroll
        for (int v = 0; v < 4; ++v) { best[v] = 3.402823466e38f; bi[v] = 0; }

        for (int base = 0; base < KC; base += CH) {
            const int rows = (KC - base) < CH ? (KC - base) : CH;

            __syncthreads();   // prior chunk's readers done before overwrite

            // stage chunk: coalesced float4 global loads, TRANSPOSED LDS
            // writes into chain-major layout: elem e of row r ->
            // sC[r*RST + (e&7)*CST + (e>>3)]
            {
                const float4* g4 = (const float4*)(C + (size_t)base * DD);
                const int nf4 = rows * 32;
                for (int i = tid; i < nf4; i += 256) {
                    float4 v = g4[i];
                    const int row = i >> 5;
                    const int j   = i & 31;         // float4 index in row
                    const int c0  = (j & 1) * 4;    // chains c0..c0+3, same k
                    const int k   = j >> 1;
                    float* dst = sC + row * RST + c0 * CST + k;
                    dst[0 * CST] = v.x;
                    dst[1 * CST] = v.y;
                    dst[2 * CST] = v.z;
                    dst[3 * CST] = v.w;
                }
            }
            // cn for this chunk (from global; bitwise-same chain code as R3)
            if (tid < rows) {
                const float* cr = C + (size_t)(base + tid) * DD;
                float p[8];
                #pragma unroll
                for (int j = 0; j < 8; ++j) { float v = cr[j]; p[j] = v * v; }
                #pragma unroll
                for (int i = 8; i < DD; i += 8) {
                    #pragma unroll
                    for (int j = 0; j < 8; ++j) { float v = cr[i + j]; p[j] += v * v; }
                }
                cn_s[tid] = ((p[0]+p[1]) + (p[2]+p[3])) + ((p[4]+p[5]) + (p[6]+p[7]));
            }
            __syncthreads();

            #pragma unroll 2
            for (int kk = 0; kk < rows; ++kk) {
                // this lane's chain: 16 contiguous floats, 4x ds_read_b128
                const float4* cr4 = (const float4*)(sC + kk * RST + c * CST);
                float pa[4];
                {   // k = 0..3 ; chain head is a MUL (reference chain order)
                    float4 a = cr4[0];
                    #pragma unroll
                    for (int v = 0; v < 4; ++v) {
                        pa[v]  = rA[v][0] * a.x;
                        pa[v] += rA[v][1] * a.y;
                        pa[v] += rA[v][2] * a.z;
                        pa[v] += rA[v][3] * a.w;
                    }
                }
                #pragma unroll
                for (int t = 1; t < 4; ++t) {
                    float4 a = cr4[t];
                    #pragma unroll
                    for (int v = 0; v < 4; ++v) {
                        pa[v] += rA[v][4*t    ] * a.x;
                        pa[v] += rA[v][4*t + 1] * a.y;
                        pa[v] += rA[v][4*t + 2] * a.z;
                        pa[v] += rA[v][4*t + 3] * a.w;
                    }
                }
                const float cn = cn_s[kk];
                #pragma unroll
                for (int v = 0; v < 4; ++v) {
                    float s = pa[v];
                    s = bfly_add<0xB1>(s);      // p_c + p_{c^1}
                    s = bfly_add<0x4E>(s);      // -> T_h
                    s = bfly_add<0x141>(s);     // -> dot, identical in 8 lanes
                    float dist = (rn[v] - 2.0f * s) + cn;   // reference association
                    if (dist < best[v]) { best[v] = dist; bi[v] = base + kk; }  // strict <
                }
            }
        }

        // rec += c ; res = x - rec (elementwise, this lane's chain only)
        #pragma unroll
        for (int v = 0; v < 4; ++v) {
            const size_t n = vbase + v;
            const float* cw = C + (size_t)bi[v] * DD + c;
            const float* xr = x + n * DD + c;
            float* so = out_side + ((size_t)m * NV + n) * DD + c;
            #pragma unroll
            for (int k = 0; k < 16; ++k) {
                float cv = cw[8 * k];
                float xv = xr[8 * k];
                cA[v][k] += cv;
                rA[v][k] = xv - cA[v][k];
                so[8 * k] = cA[v][k];
            }
        }

        // one-hot codes: group-uniform bi; lane c writes columns
        // [c*32, c*32+32) of each of the group's 4 rows
        #pragma unroll
        for (int v = 0; v < 4; ++v) {
            const size_t n = vbase + v;
            float* crow = out_codes + n * (size_t)(MS * KC) + (size_t)m * KC;
            const int b = bi[v];
            #pragma unroll
            for (int j4 = 0; j4 < 32; j4 += 4) {
                const int j = c * 32 + j4;
                float4 w;
                w.x = (b == j    ) ? 1.0f : 0.0f;
                w.y = (b == j + 1) ? 1.0f : 0.0f;
                w.z = (b == j + 2) ? 1.0f : 0.0f;
                w.w = (b == j + 3) ? 1.0f : 0.0f;
                *(float4*)(crow + j) = w;
            }
        }
    }

    // final recon (this lane's chain)
    #pragma unroll
    for (int v = 0; v < 4; ++v) {
        float* ro = out_recon + (vbase + v) * DD + c;
        #pragma unroll
        for (int k = 0; k < 16; ++k) ro[8 * k] = cA[v][k];
    }
}

extern "C" void kernel_launch(void* const* d_in, const int* in_sizes, int n_in,
                              void* d_out, int out_size, void* d_ws, size_t ws_size,
                              hipStream_t stream)
{
    const float* x  = (const float*)d_in[0];
    const float* cb = (const float*)d_in[1];
    float* out = (float*)d_out;
    rq_kernel<<<dim3(NV / 128), dim3(256), 0, stream>>>(x, cb, out);
}